// Round 19
// baseline (112.829 us; speedup 1.0000x reference)
//
#include <hip/hip_runtime.h>

typedef __attribute__((ext_vector_type(8))) short bf16x8;
typedef __attribute__((ext_vector_type(4))) float f32x4;
typedef __attribute__((ext_vector_type(16))) float f32x16;
typedef unsigned short u16;
typedef unsigned int u32;
typedef __attribute__((ext_vector_type(4))) unsigned int u32x4;

#define DEV static __device__ __forceinline__

DEV u16 f2bf(float f) {
  u32 u = __float_as_uint(f);
  u += 0x7FFFu + ((u >> 16) & 1u);
  return (u16)(u >> 16);
}
DEV float bf2f(u16 h) { return __uint_as_float(((u32)h) << 16); }

DEV void gload16(const void* g, void* l) {
  __builtin_amdgcn_global_load_lds((const __attribute__((address_space(1))) void*)g,
                                   (__attribute__((address_space(3))) void*)l, 16, 0, 0);
}

#define MFMA16(a, b, c) __builtin_amdgcn_mfma_f32_16x16x32_bf16((a), (b), (c), 0, 0, 0)
#define MFMA32(a, b, c) __builtin_amdgcn_mfma_f32_32x32x16_bf16((a), (b), (c), 0, 0, 0)

DEV u32 cvtpk(float lo, float hi) {
  u32 r;
  asm("v_cvt_pk_bf16_f32 %0, %1, %2" : "=v"(r) : "v"(lo), "v"(hi));
  return r;
}
DEV void plswap(u32& a, u32& b) {
  asm volatile("v_permlane32_swap_b32 %0, %1" : "+v"(a), "+v"(b));
}
DEV bf16x8 asbf(u32x4 v) {
  union { u32x4 u; bf16x8 b; } x;
  x.u = v;
  return x.b;
}

// raw barrier with compiler fences: no implicit vmcnt drain (unlike __syncthreads).
// Only for VALU-dominated loops (flash) — never in MFMA-dense GEMM K-loops (R15/m141).
DEV void rawbar() {
  __builtin_amdgcn_sched_barrier(0);
  asm volatile("" ::: "memory");
  __builtin_amdgcn_s_barrier();
  asm volatile("" ::: "memory");
  __builtin_amdgcn_sched_barrier(0);
}
#define VMCNT8() asm volatile("s_waitcnt vmcnt(8)" ::: "memory")
#define VMCNT0() asm volatile("s_waitcnt vmcnt(0)" ::: "memory")
#define LGKM0()  asm volatile("s_waitcnt lgkmcnt(0)" ::: "memory")

#define MAXLOG 4.6051701859880914f

// ---------------- prep: x->bf16 cvt + both weight transposes (merged, 1 launch) ----------------
__global__ __launch_bounds__(256) void k_prep(const float* __restrict__ x,
                                              u16* __restrict__ Xbf,
                                              const float* __restrict__ w_qkv,
                                              u16* __restrict__ Wqkvt,
                                              const float* __restrict__ w_out,
                                              u16* __restrict__ Woutt) {
  __shared__ u16 lds[64][72];
  int blk = blockIdx.x;
  int t = threadIdx.x;
  if (blk < 2048) {
    int i = blk * 256 + t;
    const f32x4* p = (const f32x4*)(x + (size_t)i * 8);
    f32x4 a = p[0], b = p[1];
    bf16x8 o;
    o[0] = (short)f2bf(a[0]); o[1] = (short)f2bf(a[1]);
    o[2] = (short)f2bf(a[2]); o[3] = (short)f2bf(a[3]);
    o[4] = (short)f2bf(b[0]); o[5] = (short)f2bf(b[1]);
    o[6] = (short)f2bf(b[2]); o[7] = (short)f2bf(b[3]);
    *(bf16x8*)(Xbf + (size_t)i * 8) = o;
    return;
  }
  const float* src;
  u16* dst;
  int rows, cols, bx, by;
  if (blk < 2816) {
    int q = blk - 2048;          // 768 tiles: w_qkv 1024x3072 -> 3072x1024
    src = w_qkv; dst = Wqkvt; rows = 1024; cols = 3072;
    bx = q % 48; by = q / 48;
  } else {
    int q = blk - 2816;          // 256 tiles: w_out 1024x1024 -> 1024x1024
    src = w_out; dst = Woutt; rows = 1024; cols = 1024;
    bx = q % 16; by = q / 16;
  }
  int r0 = by * 64, c0 = bx * 64;
  int r = t >> 2, cq = (t & 3) << 4;
  const float* s = src + (size_t)(r0 + r) * cols + c0 + cq;
#pragma unroll
  for (int i = 0; i < 16; i += 4) {
    f32x4 v = *(const f32x4*)(s + i);
    lds[r][cq + i + 0] = f2bf(v[0]);
    lds[r][cq + i + 1] = f2bf(v[1]);
    lds[r][cq + i + 2] = f2bf(v[2]);
    lds[r][cq + i + 3] = f2bf(v[3]);
  }
  __syncthreads();
  int c = t >> 2, rq = (t & 3) << 4;
  bf16x8 o0, o1;
#pragma unroll
  for (int i = 0; i < 8; ++i) o0[i] = (short)lds[rq + i][c];
#pragma unroll
  for (int i = 0; i < 8; ++i) o1[i] = (short)lds[rq + 8 + i][c];
  u16* d = dst + (size_t)(c0 + c) * rows + r0 + rq;
  *(bf16x8*)d = o0;
  *(bf16x8*)(d + 8) = o1;
}

// ---------------- QKV GEMM: BK=64 single-buffer (16 iters, 32 MFMA/stage) + FUSED epilogue ----------------
__global__ __launch_bounds__(256) void k_gemm_qkv(const u16* __restrict__ A,
                                                  const u16* __restrict__ Bt,
                                                  const float* __restrict__ logit_scale,
                                                  u16* __restrict__ Qn, u16* __restrict__ Kn,
                                                  u16* __restrict__ Vt,
                                                  int M, int N, int K, int nbx) {
  __shared__ __align__(16) u16 lsA[128 * 64];
  __shared__ __align__(16) u16 lsB[128 * 64];
  int tid = threadIdx.x;
  int lane = tid & 63, wave = tid >> 6;
  int wr = (wave >> 1) * 64, wc = (wave & 1) * 64;
  int nwg = gridDim.x;
  int orig = blockIdx.x;
  int wg = (orig & 7) * (nwg >> 3) + (orig >> 3);
  int bm = (wg / nbx) * 128, bn = (wg % nbx) * 128;

  f32x4 acc[4][4] = {};

  const u16* aSrc[4];
  const u16* bSrc[4];
  int lOf[4];
#pragma unroll
  for (int i = 0; i < 4; ++i) {
    int c = i * 256 + tid;
    int row = c >> 3, ch = c & 7;
    int g = ch ^ (row & 7);
    aSrc[i] = A + (size_t)(bm + row) * K + g * 8;
    bSrc[i] = Bt + (size_t)(bn + row) * K + g * 8;
    lOf[i] = c * 8;
  }

  for (int k0 = 0; k0 < K; k0 += 64) {
    __syncthreads();
#pragma unroll
    for (int i = 0; i < 4; ++i) gload16(aSrc[i] + k0, &lsA[lOf[i]]);
#pragma unroll
    for (int i = 0; i < 4; ++i) gload16(bSrc[i] + k0, &lsB[lOf[i]]);
    __syncthreads();
#pragma unroll
    for (int kk = 0; kk < 2; ++kk) {
      bf16x8 af[4], bfr[4];
#pragma unroll
      for (int m = 0; m < 4; ++m) {
        int r = wr + m * 16 + (lane & 15);
        int p = (kk * 4 + (lane >> 4)) ^ (r & 7);
        af[m] = *(const bf16x8*)&lsA[r * 64 + p * 8];
      }
#pragma unroll
      for (int n = 0; n < 4; ++n) {
        int r = wc + n * 16 + (lane & 15);
        int p = (kk * 4 + (lane >> 4)) ^ (r & 7);
        bfr[n] = *(const bf16x8*)&lsB[r * 64 + p * 8];
      }
#pragma unroll
      for (int m = 0; m < 4; ++m)
#pragma unroll
        for (int n = 0; n < 4; ++n)
          acc[m][n] = MFMA16(af[m], bfr[n], acc[m][n]);
    }
  }

  int colg = bn + wc;  // this wave's 64-col group base (one head's d-range)
  if (colg < 2048) {
    bool isQ = colg < 1024;
    int h = (colg >> 6) & 15;
    float scale = isQ ? __expf(fminf(logit_scale[h], MAXLOG)) : 1.0f;
    u16* dst = isQ ? Qn : Kn;
#pragma unroll
    for (int m = 0; m < 4; ++m) {
#pragma unroll
      for (int j = 0; j < 4; ++j) {
        float ss = 0.f;
#pragma unroll
        for (int n = 0; n < 4; ++n) ss += acc[m][n][j] * acc[m][n][j];
        ss += __shfl_xor(ss, 1, 64);
        ss += __shfl_xor(ss, 2, 64);
        ss += __shfl_xor(ss, 4, 64);
        ss += __shfl_xor(ss, 8, 64);
        float r = scale / fmaxf(sqrtf(ss), 1e-12f);
        int row = bm + wr + m * 16 + ((lane >> 4) << 2) + j;
        int b = row >> 11, tok = row & 2047;
        size_t base = ((size_t)(b * 16 + h) * 2048 + tok) * 64;
#pragma unroll
        for (int n = 0; n < 4; ++n)
          dst[base + n * 16 + (lane & 15)] = f2bf(acc[m][n][j] * r);
      }
    }
  } else {
    int h = ((colg - 2048) >> 6) & 15;
    __syncthreads();
    u16* sl = (wave < 2 ? lsA : lsB) + (wave & 1) * 2048;
    int bb = bm >> 11, bmm = bm & 2047;
    size_t vbase = ((size_t)(bb * 16 + h) * 64) * 2048;
#pragma unroll
    for (int rr = 0; rr < 2; ++rr) {
#pragma unroll
      for (int nn = 0; nn < 2; ++nn) {
        int n = rr * 2 + nn;
        int d32 = nn * 16 + (lane & 15);
        int xr = (d32 & 7) << 3;
#pragma unroll
        for (int m = 0; m < 4; ++m)
#pragma unroll
          for (int j = 0; j < 4; ++j) {
            int tok = m * 16 + ((lane >> 4) << 2) + j;
            sl[d32 * 64 + (tok ^ xr)] = f2bf(acc[m][n][j]);
          }
      }
      LGKM0();
#pragma unroll
      for (int ri = 0; ri < 4; ++ri) {
        int li = ri * 64 + lane;
        int d32 = li >> 3, c = li & 7;
        int cx = c ^ (d32 & 7);
        bf16x8 v = *(const bf16x8*)&sl[d32 * 64 + cx * 8];
        size_t dsto = vbase + (size_t)(rr * 32 + d32) * 2048 + bmm + wr + c * 8;
        *(bf16x8*)&Vt[dsto] = v;
      }
      LGKM0();
    }
  }
}

// ---------------- out-proj GEMM: BK=64 single-buffer (16 iters, 16 MFMA/stage) ----------------
__global__ __launch_bounds__(256) void k_gemm_out(const u16* __restrict__ A,
                                                  const u16* __restrict__ Bt,
                                                  float* __restrict__ Cout,
                                                  const float* __restrict__ bias,
                                                  int M, int N, int K, int nbx) {
  __shared__ __align__(16) u16 lsA[128 * 64];
  __shared__ __align__(16) u16 lsB[64 * 64];
  int tid = threadIdx.x;
  int lane = tid & 63, wave = tid >> 6;
  int wr = (wave >> 1) * 64, wc = (wave & 1) * 32;
  int nwg = gridDim.x;
  int orig = blockIdx.x;
  int wg = (orig & 7) * (nwg >> 3) + (orig >> 3);
  int bm = (wg / nbx) * 128, bn = (wg % nbx) * 64;

  f32x4 acc[4][2] = {};

  const u16* aSrc[4];
  const u16* bSrc[2];
  int lOfA[4], lOfB[2];
#pragma unroll
  for (int i = 0; i < 4; ++i) {
    int c = i * 256 + tid;
    int row = c >> 3, ch = c & 7;
    int g = ch ^ (row & 7);
    aSrc[i] = A + (size_t)(bm + row) * K + g * 8;
    lOfA[i] = c * 8;
  }
#pragma unroll
  for (int i = 0; i < 2; ++i) {
    int c = i * 256 + tid;
    int row = c >> 3, ch = c & 7;
    int g = ch ^ (row & 7);
    bSrc[i] = Bt + (size_t)(bn + row) * K + g * 8;
    lOfB[i] = c * 8;
  }

  for (int k0 = 0; k0 < K; k0 += 64) {
    __syncthreads();
#pragma unroll
    for (int i = 0; i < 4; ++i) gload16(aSrc[i] + k0, &lsA[lOfA[i]]);
#pragma unroll
    for (int i = 0; i < 2; ++i) gload16(bSrc[i] + k0, &lsB[lOfB[i]]);
    __syncthreads();
#pragma unroll
    for (int kk = 0; kk < 2; ++kk) {
      bf16x8 af[4], bfr[2];
#pragma unroll
      for (int m = 0; m < 4; ++m) {
        int r = wr + m * 16 + (lane & 15);
        int p = (kk * 4 + (lane >> 4)) ^ (r & 7);
        af[m] = *(const bf16x8*)&lsA[r * 64 + p * 8];
      }
#pragma unroll
      for (int n = 0; n < 2; ++n) {
        int r = wc + n * 16 + (lane & 15);
        int p = (kk * 4 + (lane >> 4)) ^ (r & 7);
        bfr[n] = *(const bf16x8*)&lsB[r * 64 + p * 8];
      }
#pragma unroll
      for (int m = 0; m < 4; ++m)
#pragma unroll
        for (int n = 0; n < 2; ++n)
          acc[m][n] = MFMA16(af[m], bfr[n], acc[m][n]);
    }
  }

#pragma unroll
  for (int m = 0; m < 4; ++m) {
    int row = bm + wr + m * 16 + ((lane >> 4) << 2);
#pragma unroll
    for (int n = 0; n < 2; ++n) {
      int col = bn + wc + n * 16 + (lane & 15);
      float bb = bias[col];
#pragma unroll
      for (int j = 0; j < 4; ++j)
        Cout[(size_t)(row + j) * N + col] = acc[m][n][j] + bb;
    }
  }
}

// ---------------- flash attention: 2-tile ILP per barrier interval ----------------
// Pair of KV tiles per iteration with fully independent register chains (sA*/sB*,
// separate lsm banks). The scheduler overlaps exp/pack(A) [VALU/TRANS] with QK(B)
// and PV(A) [matrix pipe] within one wave. 4 LDS buffers (66KB, 2 blocks/CU);
// stage next pair (8 gloads) -> vmcnt(8) -> bar -> compute pair -> bar.
__global__ __launch_bounds__(256, 2) void k_flash(const u16* __restrict__ Qn,
                                                  const u16* __restrict__ Kn,
                                                  const u16* __restrict__ Vt,
                                                  const float* __restrict__ logit_scale,
                                                  u16* __restrict__ AO) {
  __shared__ __align__(16) u16 lsK[4][64 * 64];
  __shared__ __align__(16) u16 lsV[4][64 * 64];
  __shared__ float l_s[4][32];
  int tid = threadIdx.x, lane = tid & 63, wave = tid >> 6;
  int r31 = lane & 31, h = lane >> 5;
  int bh = blockIdx.x, b = bh >> 4, hd = bh & 15;
  int qw = blockIdx.y * 128 + wave * 32;
  const u16* Q = Qn + (size_t)bh * 2048 * 64;
  const u16* Kb = Kn + (size_t)bh * 2048 * 64;
  const u16* Vb = Vt + (size_t)bh * 64 * 2048;

  float negC = -__expf(fminf(logit_scale[hd], MAXLOG));

  bf16x8 qB[4];
#pragma unroll
  for (int ks = 0; ks < 4; ++ks)
    qB[ks] = *(const bf16x8*)&Q[(size_t)(qw + r31) * 64 + ks * 16 + h * 8];

  size_t kGO[2], vGO[2];
  int lOff[2];
#pragma unroll
  for (int j = 0; j < 2; ++j) {
    int s = j * 256 + tid;
    int row = s >> 3, ch = s & 7, g = ch ^ (row & 7);
    kGO[j] = (size_t)row * 64 + g * 8;
    vGO[j] = (size_t)row * 2048 + g * 8;
    lOff[j] = s * 8;
  }

  int off[2][4];
#pragma unroll
  for (int a = 0; a < 2; ++a)
#pragma unroll
    for (int ks = 0; ks < 4; ++ks)
      off[a][ks] = (a * 32 + r31) * 64 + ((((ks << 1) | h) ^ (r31 & 7)) << 3);

  f32x16 o0, o1;
#pragma unroll
  for (int i = 0; i < 16; ++i) { o0[i] = 0.f; o1[i] = 0.f; }
  float lsm[8] = {0.f, 0.f, 0.f, 0.f, 0.f, 0.f, 0.f, 0.f};

#define STAGE(dstbuf, kvt)                                          \
  {                                                                 \
    size_t kv0 = (size_t)(kvt) * 64;                                \
    gload16(Kb + kv0 * 64 + kGO[0], &lsK[dstbuf][lOff[0]]);         \
    gload16(Kb + kv0 * 64 + kGO[1], &lsK[dstbuf][lOff[1]]);         \
    gload16(Vb + kv0 + vGO[0], &lsV[dstbuf][lOff[0]]);              \
    gload16(Vb + kv0 + vGO[1], &lsV[dstbuf][lOff[1]]);              \
  }

// QK for one tile from buf BUF into S0,S1
#define QKT(S0, S1, BUF)                                            \
  {                                                                 \
    bf16x8 k0f[4], k1f[4];                                          \
    _Pragma("unroll") for (int ks = 0; ks < 4; ++ks) {              \
      k0f[ks] = *(const bf16x8*)&lsK[BUF][off[0][ks]];              \
      k1f[ks] = *(const bf16x8*)&lsK[BUF][off[1][ks]];              \
    }                                                               \
    _Pragma("unroll") for (int i = 0; i < 16; ++i) { S0[i] = negC; S1[i] = negC; } \
    __builtin_amdgcn_s_setprio(1);                                  \
    _Pragma("unroll") for (int ks = 0; ks < 4; ++ks) {              \
      S0 = MFMA32(k0f[ks], qB[ks], S0);                             \
      S1 = MFMA32(k1f[ks], qB[ks], S1);                             \
    }                                                               \
    __builtin_amdgcn_s_setprio(0);                                  \
  }

// exp + lsum (bank LB) for one tile's S-state
#define EXPT(S0, S1, LB)                                            \
  _Pragma("unroll") for (int i = 0; i < 16; ++i) {                  \
    float e0 = __expf(S0[i]);                                       \
    float e1 = __expf(S1[i]);                                       \
    lsm[(LB) + (i & 3)] += e0 + e1;                                 \
    S0[i] = e0; S1[i] = e1;                                         \
  }

// pack + PV for one tile from buf BUF
#define PVT(S0, S1, BUF)                                            \
  {                                                                 \
    bf16x8 v0f[4], v1f[4];                                          \
    _Pragma("unroll") for (int ks = 0; ks < 4; ++ks) {              \
      v0f[ks] = *(const bf16x8*)&lsV[BUF][off[0][ks]];              \
      v1f[ks] = *(const bf16x8*)&lsV[BUF][off[1][ks]];              \
    }                                                               \
    bf16x8 pa[4];                                                   \
    {                                                               \
      u32 c0 = cvtpk(S0[0], S0[1]),  c1 = cvtpk(S0[2], S0[3]);      \
      u32 c2 = cvtpk(S0[4], S0[5]),  c3 = cvtpk(S0[6], S0[7]);      \
      u32 c4 = cvtpk(S0[8], S0[9]),  c5 = cvtpk(S0[10], S0[11]);    \
      u32 c6 = cvtpk(S0[12], S0[13]), c7 = cvtpk(S0[14], S0[15]);   \
      plswap(c0, c2); plswap(c1, c3); plswap(c4, c6); plswap(c5, c7);\
      pa[0] = asbf((u32x4){c0, c1, c2, c3});                        \
      pa[1] = asbf((u32x4){c4, c5, c6, c7});                        \
      u32 d0 = cvtpk(S1[0], S1[1]),  d1 = cvtpk(S1[2], S1[3]);      \
      u32 d2 = cvtpk(S1[4], S1[5]),  d3 = cvtpk(S1[6], S1[7]);      \
      u32 d4 = cvtpk(S1[8], S1[9]),  d5 = cvtpk(S1[10], S1[11]);    \
      u32 d6 = cvtpk(S1[12], S1[13]), d7 = cvtpk(S1[14], S1[15]);   \
      plswap(d0, d2); plswap(d1, d3); plswap(d4, d6); plswap(d5, d7);\
      pa[2] = asbf((u32x4){d0, d1, d2, d3});                        \
      pa[3] = asbf((u32x4){d4, d5, d6, d7});                        \
    }                                                               \
    __builtin_amdgcn_s_setprio(1);                                  \
    _Pragma("unroll") for (int ks = 0; ks < 4; ++ks) {              \
      o0 = MFMA32(pa[ks], v0f[ks], o0);                             \
      o1 = MFMA32(pa[ks], v1f[ks], o1);                             \
    }                                                               \
    __builtin_amdgcn_s_setprio(0);                                  \
  }

  // prologue: stage pair 0 (tiles 0,1 -> bufs 0,1)
  STAGE(0, 0);
  STAGE(1, 1);

#pragma unroll 1
  for (int p = 0; p < 16; ++p) {
    int cur = (p & 1) << 1;     // bufs {0,1} or {2,3}
    if (p < 15) {
      STAGE(cur ^ 2, 2 * p + 2);
      STAGE((cur ^ 2) + 1, 2 * p + 3);
      VMCNT8();                 // wait current pair's 8 loads; next pair's stay in flight
    } else {
      VMCNT0();
    }
    rawbar();

    f32x16 sA0, sA1, sB0, sB1;
    QKT(sA0, sA1, cur);
    QKT(sB0, sB1, cur + 1);
    EXPT(sA0, sA1, 0);
    PVT(sA0, sA1, cur);
    EXPT(sB0, sB1, 4);
    PVT(sB0, sB1, cur + 1);

    rawbar();
  }
#undef STAGE
#undef QKT
#undef EXPT
#undef PVT

  float lsum = ((lsm[0] + lsm[1]) + (lsm[2] + lsm[3])) +
               ((lsm[4] + lsm[5]) + (lsm[6] + lsm[7]));
  float ltot = lsum + __shfl_xor(lsum, 32, 64);
  if (h == 0) l_s[wave][r31] = 1.0f / ltot;
  __syncthreads();

#pragma unroll
  for (int r = 0; r < 16; ++r) {
    int cr = (r & 3) + ((r >> 2) << 3) + (h << 2);
    int qr = qw + cr;
    float li = l_s[wave][cr];
    size_t base = ((size_t)(b * 2048 + qr)) * 1024 + hd * 64;
    AO[base + r31] = f2bf(o0[r] * li);
    AO[base + 32 + r31] = f2bf(o1[r] * li);
  }
}

// ---------------- host ----------------
extern "C" void kernel_launch(void* const* d_in, const int* in_sizes, int n_in,
                              void* d_out, int out_size, void* d_ws, size_t ws_size,
                              hipStream_t stream) {
  const float* x = (const float*)d_in[0];
  const float* w_qkv = (const float*)d_in[1];
  const float* w_out = (const float*)d_in[2];
  const float* b_out = (const float*)d_in[3];
  const float* logit_scale = (const float*)d_in[4];

  char* ws = (char*)d_ws;
  u16* Xbf   = (u16*)(ws);                   // 8 MB  [4096][1024]
  u16* Wqkvt = (u16*)(ws + (8ll << 20));     // 6 MB  [3072][1024]
  u16* Woutt = (u16*)(ws + (14ll << 20));    // 2 MB  [1024][1024]
  u16* Qn    = (u16*)(ws + (16ll << 20));    // 8 MB  [2][16][2048][64]
  u16* Kn    = (u16*)(ws + (24ll << 20));    // 8 MB
  u16* Vt    = (u16*)(ws + (32ll << 20));    // 8 MB  [2][16][64][2048]
  u16* AO    = Xbf;                          // reuse x-bf16 region [4096][1024]
  float* out = (float*)d_out;

  k_prep<<<3072, 256, 0, stream>>>(x, Xbf, w_qkv, Wqkvt, w_out, Woutt);
  k_gemm_qkv<<<768, 256, 0, stream>>>(Xbf, Wqkvt, logit_scale, Qn, Kn, Vt,
                                      4096, 3072, 1024, 24);
  k_flash<<<dim3(32, 16), 256, 0, stream>>>(Qn, Kn, Vt, logit_scale, AO);
  k_gemm_out<<<512, 256, 0, stream>>>(AO, Woutt, out, b_out,
                                      4096, 1024, 1024, 16);
}

// Round 20
// 109.707 us; speedup vs baseline: 1.0285x; 1.0285x over previous
//
#include <hip/hip_runtime.h>

typedef __attribute__((ext_vector_type(8))) short bf16x8;
typedef __attribute__((ext_vector_type(4))) float f32x4;
typedef __attribute__((ext_vector_type(16))) float f32x16;
typedef unsigned short u16;
typedef unsigned int u32;
typedef __attribute__((ext_vector_type(4))) unsigned int u32x4;

#define DEV static __device__ __forceinline__

DEV u16 f2bf(float f) {
  u32 u = __float_as_uint(f);
  u += 0x7FFFu + ((u >> 16) & 1u);
  return (u16)(u >> 16);
}
DEV float bf2f(u16 h) { return __uint_as_float(((u32)h) << 16); }

DEV void gload16(const void* g, void* l) {
  __builtin_amdgcn_global_load_lds((const __attribute__((address_space(1))) void*)g,
                                   (__attribute__((address_space(3))) void*)l, 16, 0, 0);
}

#define MFMA16(a, b, c) __builtin_amdgcn_mfma_f32_16x16x32_bf16((a), (b), (c), 0, 0, 0)
#define MFMA32(a, b, c) __builtin_amdgcn_mfma_f32_32x32x16_bf16((a), (b), (c), 0, 0, 0)

DEV u32 cvtpk(float lo, float hi) {
  u32 r;
  asm("v_cvt_pk_bf16_f32 %0, %1, %2" : "=v"(r) : "v"(lo), "v"(hi));
  return r;
}
DEV void plswap(u32& a, u32& b) {
  asm volatile("v_permlane32_swap_b32 %0, %1" : "+v"(a), "+v"(b));
}
DEV bf16x8 asbf(u32x4 v) {
  union { u32x4 u; bf16x8 b; } x;
  x.u = v;
  return x.b;
}

// raw barrier with compiler fences: no implicit vmcnt drain (unlike __syncthreads).
// Only for VALU-dominated loops (flash) — never in MFMA-dense GEMM K-loops (R15/m141).
DEV void rawbar() {
  __builtin_amdgcn_sched_barrier(0);
  asm volatile("" ::: "memory");
  __builtin_amdgcn_s_barrier();
  asm volatile("" ::: "memory");
  __builtin_amdgcn_sched_barrier(0);
}
#define VMCNT4() asm volatile("s_waitcnt vmcnt(4)" ::: "memory")
#define VMCNT0() asm volatile("s_waitcnt vmcnt(0)" ::: "memory")
#define LGKM0()  asm volatile("s_waitcnt lgkmcnt(0)" ::: "memory")

#define MAXLOG 4.6051701859880914f

// ---------------- prep: x->bf16 cvt + both weight transposes (merged, 1 launch) ----------------
__global__ __launch_bounds__(256) void k_prep(const float* __restrict__ x,
                                              u16* __restrict__ Xbf,
                                              const float* __restrict__ w_qkv,
                                              u16* __restrict__ Wqkvt,
                                              const float* __restrict__ w_out,
                                              u16* __restrict__ Woutt) {
  __shared__ u16 lds[64][72];
  int blk = blockIdx.x;
  int t = threadIdx.x;
  if (blk < 2048) {
    int i = blk * 256 + t;
    const f32x4* p = (const f32x4*)(x + (size_t)i * 8);
    f32x4 a = p[0], b = p[1];
    bf16x8 o;
    o[0] = (short)f2bf(a[0]); o[1] = (short)f2bf(a[1]);
    o[2] = (short)f2bf(a[2]); o[3] = (short)f2bf(a[3]);
    o[4] = (short)f2bf(b[0]); o[5] = (short)f2bf(b[1]);
    o[6] = (short)f2bf(b[2]); o[7] = (short)f2bf(b[3]);
    *(bf16x8*)(Xbf + (size_t)i * 8) = o;
    return;
  }
  const float* src;
  u16* dst;
  int rows, cols, bx, by;
  if (blk < 2816) {
    int q = blk - 2048;          // 768 tiles: w_qkv 1024x3072 -> 3072x1024
    src = w_qkv; dst = Wqkvt; rows = 1024; cols = 3072;
    bx = q % 48; by = q / 48;
  } else {
    int q = blk - 2816;          // 256 tiles: w_out 1024x1024 -> 1024x1024
    src = w_out; dst = Woutt; rows = 1024; cols = 1024;
    bx = q % 16; by = q / 16;
  }
  int r0 = by * 64, c0 = bx * 64;
  int r = t >> 2, cq = (t & 3) << 4;
  const float* s = src + (size_t)(r0 + r) * cols + c0 + cq;
#pragma unroll
  for (int i = 0; i < 16; i += 4) {
    f32x4 v = *(const f32x4*)(s + i);
    lds[r][cq + i + 0] = f2bf(v[0]);
    lds[r][cq + i + 1] = f2bf(v[1]);
    lds[r][cq + i + 2] = f2bf(v[2]);
    lds[r][cq + i + 3] = f2bf(v[3]);
  }
  __syncthreads();
  int c = t >> 2, rq = (t & 3) << 4;
  bf16x8 o0, o1;
#pragma unroll
  for (int i = 0; i < 8; ++i) o0[i] = (short)lds[rq + i][c];
#pragma unroll
  for (int i = 0; i < 8; ++i) o1[i] = (short)lds[rq + 8 + i][c];
  u16* d = dst + (size_t)(c0 + c) * rows + r0 + rq;
  *(bf16x8*)d = o0;
  *(bf16x8*)(d + 8) = o1;
}

// ---------------- QKV GEMM: BK=64 single-buffer (16 iters, 32 MFMA/stage) + FUSED epilogue ----------------
__global__ __launch_bounds__(256) void k_gemm_qkv(const u16* __restrict__ A,
                                                  const u16* __restrict__ Bt,
                                                  const float* __restrict__ logit_scale,
                                                  u16* __restrict__ Qn, u16* __restrict__ Kn,
                                                  u16* __restrict__ Vt,
                                                  int M, int N, int K, int nbx) {
  __shared__ __align__(16) u16 lsA[128 * 64];
  __shared__ __align__(16) u16 lsB[128 * 64];
  int tid = threadIdx.x;
  int lane = tid & 63, wave = tid >> 6;
  int wr = (wave >> 1) * 64, wc = (wave & 1) * 64;
  int nwg = gridDim.x;
  int orig = blockIdx.x;
  int wg = (orig & 7) * (nwg >> 3) + (orig >> 3);
  int bm = (wg / nbx) * 128, bn = (wg % nbx) * 128;

  f32x4 acc[4][4] = {};

  const u16* aSrc[4];
  const u16* bSrc[4];
  int lOf[4];
#pragma unroll
  for (int i = 0; i < 4; ++i) {
    int c = i * 256 + tid;
    int row = c >> 3, ch = c & 7;
    int g = ch ^ (row & 7);
    aSrc[i] = A + (size_t)(bm + row) * K + g * 8;
    bSrc[i] = Bt + (size_t)(bn + row) * K + g * 8;
    lOf[i] = c * 8;
  }

  for (int k0 = 0; k0 < K; k0 += 64) {
    __syncthreads();
#pragma unroll
    for (int i = 0; i < 4; ++i) gload16(aSrc[i] + k0, &lsA[lOf[i]]);
#pragma unroll
    for (int i = 0; i < 4; ++i) gload16(bSrc[i] + k0, &lsB[lOf[i]]);
    __syncthreads();
#pragma unroll
    for (int kk = 0; kk < 2; ++kk) {
      bf16x8 af[4], bfr[4];
#pragma unroll
      for (int m = 0; m < 4; ++m) {
        int r = wr + m * 16 + (lane & 15);
        int p = (kk * 4 + (lane >> 4)) ^ (r & 7);
        af[m] = *(const bf16x8*)&lsA[r * 64 + p * 8];
      }
#pragma unroll
      for (int n = 0; n < 4; ++n) {
        int r = wc + n * 16 + (lane & 15);
        int p = (kk * 4 + (lane >> 4)) ^ (r & 7);
        bfr[n] = *(const bf16x8*)&lsB[r * 64 + p * 8];
      }
#pragma unroll
      for (int m = 0; m < 4; ++m)
#pragma unroll
        for (int n = 0; n < 4; ++n)
          acc[m][n] = MFMA16(af[m], bfr[n], acc[m][n]);
    }
  }

  int colg = bn + wc;  // this wave's 64-col group base (one head's d-range)
  if (colg < 2048) {
    bool isQ = colg < 1024;
    int h = (colg >> 6) & 15;
    float scale = isQ ? __expf(fminf(logit_scale[h], MAXLOG)) : 1.0f;
    u16* dst = isQ ? Qn : Kn;
#pragma unroll
    for (int m = 0; m < 4; ++m) {
#pragma unroll
      for (int j = 0; j < 4; ++j) {
        float ss = 0.f;
#pragma unroll
        for (int n = 0; n < 4; ++n) ss += acc[m][n][j] * acc[m][n][j];
        ss += __shfl_xor(ss, 1, 64);
        ss += __shfl_xor(ss, 2, 64);
        ss += __shfl_xor(ss, 4, 64);
        ss += __shfl_xor(ss, 8, 64);
        float r = scale / fmaxf(sqrtf(ss), 1e-12f);
        int row = bm + wr + m * 16 + ((lane >> 4) << 2) + j;
        int b = row >> 11, tok = row & 2047;
        size_t base = ((size_t)(b * 16 + h) * 2048 + tok) * 64;
#pragma unroll
        for (int n = 0; n < 4; ++n)
          dst[base + n * 16 + (lane & 15)] = f2bf(acc[m][n][j] * r);
      }
    }
  } else {
    int h = ((colg - 2048) >> 6) & 15;
    __syncthreads();
    u16* sl = (wave < 2 ? lsA : lsB) + (wave & 1) * 2048;
    int bb = bm >> 11, bmm = bm & 2047;
    size_t vbase = ((size_t)(bb * 16 + h) * 64) * 2048;
#pragma unroll
    for (int rr = 0; rr < 2; ++rr) {
#pragma unroll
      for (int nn = 0; nn < 2; ++nn) {
        int n = rr * 2 + nn;
        int d32 = nn * 16 + (lane & 15);
        int xr = (d32 & 7) << 3;
#pragma unroll
        for (int m = 0; m < 4; ++m)
#pragma unroll
          for (int j = 0; j < 4; ++j) {
            int tok = m * 16 + ((lane >> 4) << 2) + j;
            sl[d32 * 64 + (tok ^ xr)] = f2bf(acc[m][n][j]);
          }
      }
      LGKM0();
#pragma unroll
      for (int ri = 0; ri < 4; ++ri) {
        int li = ri * 64 + lane;
        int d32 = li >> 3, c = li & 7;
        int cx = c ^ (d32 & 7);
        bf16x8 v = *(const bf16x8*)&sl[d32 * 64 + cx * 8];
        size_t dsto = vbase + (size_t)(rr * 32 + d32) * 2048 + bmm + wr + c * 8;
        *(bf16x8*)&Vt[dsto] = v;
      }
      LGKM0();
    }
  }
}

// ---------------- out-proj GEMM: BK=64 single-buffer (16 iters, 16 MFMA/stage) ----------------
__global__ __launch_bounds__(256) void k_gemm_out(const u16* __restrict__ A,
                                                  const u16* __restrict__ Bt,
                                                  float* __restrict__ Cout,
                                                  const float* __restrict__ bias,
                                                  int M, int N, int K, int nbx) {
  __shared__ __align__(16) u16 lsA[128 * 64];
  __shared__ __align__(16) u16 lsB[64 * 64];
  int tid = threadIdx.x;
  int lane = tid & 63, wave = tid >> 6;
  int wr = (wave >> 1) * 64, wc = (wave & 1) * 32;
  int nwg = gridDim.x;
  int orig = blockIdx.x;
  int wg = (orig & 7) * (nwg >> 3) + (orig >> 3);
  int bm = (wg / nbx) * 128, bn = (wg % nbx) * 64;

  f32x4 acc[4][2] = {};

  const u16* aSrc[4];
  const u16* bSrc[2];
  int lOfA[4], lOfB[2];
#pragma unroll
  for (int i = 0; i < 4; ++i) {
    int c = i * 256 + tid;
    int row = c >> 3, ch = c & 7;
    int g = ch ^ (row & 7);
    aSrc[i] = A + (size_t)(bm + row) * K + g * 8;
    lOfA[i] = c * 8;
  }
#pragma unroll
  for (int i = 0; i < 2; ++i) {
    int c = i * 256 + tid;
    int row = c >> 3, ch = c & 7;
    int g = ch ^ (row & 7);
    bSrc[i] = Bt + (size_t)(bn + row) * K + g * 8;
    lOfB[i] = c * 8;
  }

  for (int k0 = 0; k0 < K; k0 += 64) {
    __syncthreads();
#pragma unroll
    for (int i = 0; i < 4; ++i) gload16(aSrc[i] + k0, &lsA[lOfA[i]]);
#pragma unroll
    for (int i = 0; i < 2; ++i) gload16(bSrc[i] + k0, &lsB[lOfB[i]]);
    __syncthreads();
#pragma unroll
    for (int kk = 0; kk < 2; ++kk) {
      bf16x8 af[4], bfr[2];
#pragma unroll
      for (int m = 0; m < 4; ++m) {
        int r = wr + m * 16 + (lane & 15);
        int p = (kk * 4 + (lane >> 4)) ^ (r & 7);
        af[m] = *(const bf16x8*)&lsA[r * 64 + p * 8];
      }
#pragma unroll
      for (int n = 0; n < 2; ++n) {
        int r = wc + n * 16 + (lane & 15);
        int p = (kk * 4 + (lane >> 4)) ^ (r & 7);
        bfr[n] = *(const bf16x8*)&lsB[r * 64 + p * 8];
      }
#pragma unroll
      for (int m = 0; m < 4; ++m)
#pragma unroll
        for (int n = 0; n < 2; ++n)
          acc[m][n] = MFMA16(af[m], bfr[n], acc[m][n]);
    }
  }

#pragma unroll
  for (int m = 0; m < 4; ++m) {
    int row = bm + wr + m * 16 + ((lane >> 4) << 2);
#pragma unroll
    for (int n = 0; n < 2; ++n) {
      int col = bn + wc + n * 16 + (lane & 15);
      float bb = bias[col];
#pragma unroll
      for (int j = 0; j < 4; ++j)
        Cout[(size_t)(row + j) * N + col] = acc[m][n][j] + bb;
    }
  }
}

// ---------------- flash attention (R14 exact 2-buffer structure: benched 48.6us floor) ----------------
__global__ __launch_bounds__(256, 2) void k_flash(const u16* __restrict__ Qn,
                                                  const u16* __restrict__ Kn,
                                                  const u16* __restrict__ Vt,
                                                  const float* __restrict__ logit_scale,
                                                  u16* __restrict__ AO) {
  __shared__ __align__(16) u16 lsK[2][64 * 64];
  __shared__ __align__(16) u16 lsV[2][64 * 64];
  __shared__ float l_s[4][32];
  int tid = threadIdx.x, lane = tid & 63, wave = tid >> 6;
  int r31 = lane & 31, h = lane >> 5;
  int bh = blockIdx.x, b = bh >> 4, hd = bh & 15;
  int qw = blockIdx.y * 128 + wave * 32;
  const u16* Q = Qn + (size_t)bh * 2048 * 64;
  const u16* Kb = Kn + (size_t)bh * 2048 * 64;
  const u16* Vb = Vt + (size_t)bh * 64 * 2048;

  float negC = -__expf(fminf(logit_scale[hd], MAXLOG));

  bf16x8 qB[4];
#pragma unroll
  for (int ks = 0; ks < 4; ++ks)
    qB[ks] = *(const bf16x8*)&Q[(size_t)(qw + r31) * 64 + ks * 16 + h * 8];

  size_t kGO[2], vGO[2];
  int lOff[2];
#pragma unroll
  for (int j = 0; j < 2; ++j) {
    int s = j * 256 + tid;
    int row = s >> 3, ch = s & 7, g = ch ^ (row & 7);
    kGO[j] = (size_t)row * 64 + g * 8;
    vGO[j] = (size_t)row * 2048 + g * 8;
    lOff[j] = s * 8;
  }

  int off[2][4];
#pragma unroll
  for (int a = 0; a < 2; ++a)
#pragma unroll
    for (int ks = 0; ks < 4; ++ks)
      off[a][ks] = (a * 32 + r31) * 64 + ((((ks << 1) | h) ^ (r31 & 7)) << 3);

  f32x16 o0, o1;
#pragma unroll
  for (int i = 0; i < 16; ++i) { o0[i] = 0.f; o1[i] = 0.f; }
  float lsm[4] = {0.f, 0.f, 0.f, 0.f};

#define STAGE(dstbuf, kvt)                                          \
  {                                                                 \
    size_t kv0 = (size_t)(kvt) * 64;                                \
    gload16(Kb + kv0 * 64 + kGO[0], &lsK[dstbuf][lOff[0]]);         \
    gload16(Kb + kv0 * 64 + kGO[1], &lsK[dstbuf][lOff[1]]);         \
    gload16(Vb + kv0 + vGO[0], &lsV[dstbuf][lOff[0]]);              \
    gload16(Vb + kv0 + vGO[1], &lsV[dstbuf][lOff[1]]);              \
  }

  STAGE(0, 0);

#pragma unroll 1
  for (int t = 0; t < 32; ++t) {
    int cur = t & 1;
    if (t < 31) {
      STAGE(cur ^ 1, t + 1);
      VMCNT4();
    } else {
      VMCNT0();
    }
    rawbar();
    const u16* Kl = lsK[cur];
    const u16* Vl = lsV[cur];

    f32x16 s0, s1;
#pragma unroll
    for (int i = 0; i < 16; ++i) { s0[i] = negC; s1[i] = negC; }
    bf16x8 k0f[4], k1f[4];
#pragma unroll
    for (int ks = 0; ks < 4; ++ks) {
      k0f[ks] = *(const bf16x8*)&Kl[off[0][ks]];
      k1f[ks] = *(const bf16x8*)&Kl[off[1][ks]];
    }
    __builtin_amdgcn_s_setprio(1);
#pragma unroll
    for (int ks = 0; ks < 4; ++ks) {
      s0 = MFMA32(k0f[ks], qB[ks], s0);
      s1 = MFMA32(k1f[ks], qB[ks], s1);
    }
    __builtin_amdgcn_s_setprio(0);

    bf16x8 v0f[4], v1f[4];
#pragma unroll
    for (int ks = 0; ks < 4; ++ks) {
      v0f[ks] = *(const bf16x8*)&Vl[off[0][ks]];
      v1f[ks] = *(const bf16x8*)&Vl[off[1][ks]];
    }

#pragma unroll
    for (int i = 0; i < 16; ++i) {
      float e0 = __expf(s0[i]);
      float e1 = __expf(s1[i]);
      lsm[i & 3] += e0 + e1;
      s0[i] = e0; s1[i] = e1;
    }

    bf16x8 pa[4];
    {
      u32 c0 = cvtpk(s0[0], s0[1]),  c1 = cvtpk(s0[2], s0[3]);
      u32 c2 = cvtpk(s0[4], s0[5]),  c3 = cvtpk(s0[6], s0[7]);
      u32 c4 = cvtpk(s0[8], s0[9]),  c5 = cvtpk(s0[10], s0[11]);
      u32 c6 = cvtpk(s0[12], s0[13]), c7 = cvtpk(s0[14], s0[15]);
      plswap(c0, c2); plswap(c1, c3); plswap(c4, c6); plswap(c5, c7);
      pa[0] = asbf((u32x4){c0, c1, c2, c3});
      pa[1] = asbf((u32x4){c4, c5, c6, c7});
      u32 d0 = cvtpk(s1[0], s1[1]),  d1 = cvtpk(s1[2], s1[3]);
      u32 d2 = cvtpk(s1[4], s1[5]),  d3 = cvtpk(s1[6], s1[7]);
      u32 d4 = cvtpk(s1[8], s1[9]),  d5 = cvtpk(s1[10], s1[11]);
      u32 d6 = cvtpk(s1[12], s1[13]), d7 = cvtpk(s1[14], s1[15]);
      plswap(d0, d2); plswap(d1, d3); plswap(d4, d6); plswap(d5, d7);
      pa[2] = asbf((u32x4){d0, d1, d2, d3});
      pa[3] = asbf((u32x4){d4, d5, d6, d7});
    }

    __builtin_amdgcn_s_setprio(1);
#pragma unroll
    for (int ks = 0; ks < 4; ++ks) {
      o0 = MFMA32(pa[ks], v0f[ks], o0);
      o1 = MFMA32(pa[ks], v1f[ks], o1);
    }
    __builtin_amdgcn_s_setprio(0);

    rawbar();
  }
#undef STAGE

  float lsum = (lsm[0] + lsm[1]) + (lsm[2] + lsm[3]);
  float ltot = lsum + __shfl_xor(lsum, 32, 64);
  if (h == 0) l_s[wave][r31] = 1.0f / ltot;
  __syncthreads();

#pragma unroll
  for (int r = 0; r < 16; ++r) {
    int cr = (r & 3) + ((r >> 2) << 3) + (h << 2);
    int qr = qw + cr;
    float li = l_s[wave][cr];
    size_t base = ((size_t)(b * 2048 + qr)) * 1024 + hd * 64;
    AO[base + r31] = f2bf(o0[r] * li);
    AO[base + 32 + r31] = f2bf(o1[r] * li);
  }
}

// ---------------- host ----------------
extern "C" void kernel_launch(void* const* d_in, const int* in_sizes, int n_in,
                              void* d_out, int out_size, void* d_ws, size_t ws_size,
                              hipStream_t stream) {
  const float* x = (const float*)d_in[0];
  const float* w_qkv = (const float*)d_in[1];
  const float* w_out = (const float*)d_in[2];
  const float* b_out = (const float*)d_in[3];
  const float* logit_scale = (const float*)d_in[4];

  char* ws = (char*)d_ws;
  u16* Xbf   = (u16*)(ws);                   // 8 MB  [4096][1024]
  u16* Wqkvt = (u16*)(ws + (8ll << 20));     // 6 MB  [3072][1024]
  u16* Woutt = (u16*)(ws + (14ll << 20));    // 2 MB  [1024][1024]
  u16* Qn    = (u16*)(ws + (16ll << 20));    // 8 MB  [2][16][2048][64]
  u16* Kn    = (u16*)(ws + (24ll << 20));    // 8 MB
  u16* Vt    = (u16*)(ws + (32ll << 20));    // 8 MB  [2][16][64][2048]
  u16* AO    = Xbf;                          // reuse x-bf16 region [4096][1024]
  float* out = (float*)d_out;

  k_prep<<<3072, 256, 0, stream>>>(x, Xbf, w_qkv, Wqkvt, w_out, Woutt);
  k_gemm_qkv<<<768, 256, 0, stream>>>(Xbf, Wqkvt, logit_scale, Qn, Kn, Vt,
                                      4096, 3072, 1024, 24);
  k_flash<<<dim3(32, 16), 256, 0, stream>>>(Qn, Kn, Vt, logit_scale, AO);
  k_gemm_out<<<512, 256, 0, stream>>>(AO, Woutt, out, b_out,
                                      4096, 1024, 1024, 16);
}